// Round 2
// baseline (4747.787 us; speedup 1.0000x reference)
//
#include <hip/hip_runtime.h>

// ---------------------------------------------------------------------------
// VQ-VAE forward, fp32, round 2: fix latency-bound conv structure.
// Outputs in d_out (float32, concatenated): y[6291456], loss[1], idx[32768]
// ---------------------------------------------------------------------------

// ---- v1 generic direct conv (kept for enc1, CIN=3) ----
template<int R,int S,int CIN,int COUT,int STR,int PAD,int BLK,int PPT,int ACT>
__global__ __launch_bounds__(BLK) void conv_fp32(
    const float* __restrict__ x, const float* __restrict__ w,
    const float* __restrict__ bias, float* __restrict__ y,
    int N, int Hin, int Win, int Hout, int Wout)
{
    constexpr int GPB = BLK / COUT;
    const int t = threadIdx.x;
    const int f = t % COUT;
    const int g = t / COUT;
    const int base = (blockIdx.x * GPB + g) * PPT;
    const int HW = Hout * Wout;

    int nn[PPT], ho[PPT], wo[PPT];
    float acc[PPT];
    const float bv = bias[f];
#pragma unroll
    for (int j = 0; j < PPT; ++j) {
        int p = base + j;
        nn[j] = p / HW;
        int rem = p - nn[j]*HW;
        ho[j] = rem / Wout;
        wo[j] = rem - ho[j]*Wout;
        acc[j] = bv;
    }
#pragma unroll
    for (int r = 0; r < R; ++r) {
#pragma unroll
        for (int s = 0; s < S; ++s) {
            const float* wp = w + ((r*S + s)*CIN)*COUT + f;
            int xoff[PPT]; bool v[PPT];
#pragma unroll
            for (int j = 0; j < PPT; ++j) {
                int hi = ho[j]*STR - PAD + r;
                int wi = wo[j]*STR - PAD + s;
                v[j] = (hi >= 0) && (hi < Hin) && (wi >= 0) && (wi < Win);
                xoff[j] = v[j] ? ((nn[j]*Hin + hi)*Win + wi)*CIN : 0;
            }
#pragma unroll 4
            for (int c = 0; c < CIN; ++c) {
                float wv = wp[c*COUT];
#pragma unroll
                for (int j = 0; j < PPT; ++j) {
                    float xv = v[j] ? x[xoff[j] + c] : 0.0f;
                    acc[j] = fmaf(xv, wv, acc[j]);
                }
            }
        }
    }
#pragma unroll
    for (int j = 0; j < PPT; ++j) {
        float o = acc[j];
        if (ACT == 1) o = fmaxf(o, 0.0f);
        if (ACT == 2) o = 1.0f / (1.0f + __expf(-o));
        y[(base + j)*COUT + f] = o;
    }
}

// ---- v2 conv: float4 x loads over CIN (CIN%4==0), PPT=8 ----
template<int R,int S,int CIN,int COUT,int STR,int PAD,int BLK,int PPT,int ACT>
__global__ __launch_bounds__(BLK) void conv_v2(
    const float* __restrict__ x, const float* __restrict__ w,
    const float* __restrict__ bias, float* __restrict__ y,
    int N, int Hin, int Win, int Hout, int Wout)
{
    constexpr int GPB = BLK / COUT;
    const int t = threadIdx.x;
    const int f = t % COUT;
    const int g = t / COUT;
    const int base = (blockIdx.x * GPB + g) * PPT;
    const int HW = Hout * Wout;

    int nn[PPT], ho[PPT], wo[PPT];
    float acc[PPT];
    const float bv = bias[f];
#pragma unroll
    for (int j = 0; j < PPT; ++j) {
        int p = base + j;
        nn[j] = p / HW;
        int rem = p - nn[j]*HW;
        ho[j] = rem / Wout;
        wo[j] = rem - ho[j]*Wout;
        acc[j] = bv;
    }
#pragma unroll
    for (int r = 0; r < R; ++r) {
#pragma unroll
        for (int s = 0; s < S; ++s) {
            const float* wp = w + ((r*S + s)*CIN)*COUT + f;
            int xoff[PPT]; bool v[PPT];
#pragma unroll
            for (int j = 0; j < PPT; ++j) {
                int hi = ho[j]*STR - PAD + r;
                int wi = wo[j]*STR - PAD + s;
                v[j] = (hi >= 0) && (hi < Hin) && (wi >= 0) && (wi < Win);
                xoff[j] = v[j] ? ((nn[j]*Hin + hi)*Win + wi)*CIN : 0;
            }
#pragma unroll 2
            for (int c4 = 0; c4 < CIN/4; ++c4) {
                float4 xv[PPT];
#pragma unroll
                for (int j = 0; j < PPT; ++j) {
                    if (v[j]) xv[j] = *(const float4*)(x + xoff[j] + 4*c4);
                    else      xv[j] = make_float4(0.f,0.f,0.f,0.f);
                }
#pragma unroll
                for (int cc = 0; cc < 4; ++cc) {
                    float wv = wp[(4*c4 + cc)*COUT];
#pragma unroll
                    for (int j = 0; j < PPT; ++j) {
                        float xc = (cc==0)?xv[j].x:(cc==1)?xv[j].y:(cc==2)?xv[j].z:xv[j].w;
                        acc[j] = fmaf(xc, wv, acc[j]);
                    }
                }
            }
        }
    }
#pragma unroll
    for (int j = 0; j < PPT; ++j) {
        float o = acc[j];
        if (ACT == 1) o = fmaxf(o, 0.0f);
        if (ACT == 2) o = 1.0f / (1.0f + __expf(-o));
        y[(base + j)*COUT + f] = o;
    }
}

// ---- v2 conv-transpose 4x4 s2 (parity decomposition), float4 x loads ----
template<int CIN,int COUT,int BLK,int PPT,int ACT>
__global__ __launch_bounds__(BLK) void convt_v2(
    const float* __restrict__ x, const float* __restrict__ w,
    const float* __restrict__ bias, float* __restrict__ y,
    int N, int Hin, int Win)
{
    const int Hout = 2*Hin, Wout = 2*Win;
    const int ph = blockIdx.y >> 1, pw = blockIdx.y & 1;
    constexpr int GPB = BLK / COUT;
    const int t = threadIdx.x;
    const int f = t % COUT;
    const int g = t / COUT;
    const int base = (blockIdx.x * GPB + g) * PPT;
    const int HWs = Hin * Win;

    int nn[PPT], hh[PPT], wh[PPT];
    float acc[PPT];
    const float bv = bias[f];
#pragma unroll
    for (int j = 0; j < PPT; ++j) {
        int p = base + j;
        nn[j] = p / HWs;
        int rem = p - nn[j]*HWs;
        hh[j] = rem / Win;
        wh[j] = rem - hh[j]*Win;
        acc[j] = bv;
    }
#pragma unroll
    for (int rr = 0; rr < 2; ++rr) {
#pragma unroll
        for (int ss = 0; ss < 2; ++ss) {
            const int r = ph + 2*rr, s = pw + 2*ss;
            const float* wp = w + ((r*4 + s)*CIN)*COUT + f;
            int xoff[PPT]; bool v[PPT];
#pragma unroll
            for (int j = 0; j < PPT; ++j) {
                int xi = hh[j] + ph - 1 + rr;
                int yi = wh[j] + pw - 1 + ss;
                v[j] = (xi >= 0) && (xi < Hin) && (yi >= 0) && (yi < Win);
                xoff[j] = v[j] ? ((nn[j]*Hin + xi)*Win + yi)*CIN : 0;
            }
#pragma unroll 2
            for (int c4 = 0; c4 < CIN/4; ++c4) {
                float4 xv[PPT];
#pragma unroll
                for (int j = 0; j < PPT; ++j) {
                    if (v[j]) xv[j] = *(const float4*)(x + xoff[j] + 4*c4);
                    else      xv[j] = make_float4(0.f,0.f,0.f,0.f);
                }
#pragma unroll
                for (int cc = 0; cc < 4; ++cc) {
                    float wv = wp[(4*c4 + cc)*COUT];
#pragma unroll
                    for (int j = 0; j < PPT; ++j) {
                        float xc = (cc==0)?xv[j].x:(cc==1)?xv[j].y:(cc==2)?xv[j].z:xv[j].w;
                        acc[j] = fmaf(xc, wv, acc[j]);
                    }
                }
            }
        }
    }
#pragma unroll
    for (int j = 0; j < PPT; ++j) {
        float o = acc[j];
        if (ACT == 1) o = fmaxf(o, 0.0f);
        if (ACT == 2) o = 1.0f / (1.0f + __expf(-o));
        int ho = 2*hh[j] + ph, wo = 2*wh[j] + pw;
        y[((nn[j]*Hout + ho)*Wout + wo)*COUT + f] = o;
    }
}

// ---- dec4 dedicated kernel: convT 4x4 s2, CIN=32, COUT=3, sigmoid ----
// grid.x = n*16 + rowchunk (Hin=64, 4 rows/block), grid.y = parity (ph*2+pw)
// Thread = one parity-subimage pixel, computes all 3 output channels.
// x tile staged in LDS with col-stride 33 (33 % 32 == 1 -> conflict-free).
__global__ __launch_bounds__(256) void dec4_kernel(
    const float* __restrict__ x, const float* __restrict__ w,
    const float* __restrict__ bias, float* __restrict__ y)
{
    __shared__ float xs[6*66*33];    // 52272 B
    __shared__ float ws[4*32*3];     // per-parity taps, natural (c,f) layout

    const int ph = blockIdx.y >> 1, pw = blockIdx.y & 1;
    const int n  = blockIdx.x >> 4;
    const int R0 = (blockIdx.x & 15) * 4;
    const int t  = threadIdx.x;

    if (t < 384) {
        int tap = t / 96, rem = t - tap*96;       // rem = c*3 + f
        int rr = tap >> 1, ss = tap & 1;
        int gtap = (ph + 2*rr)*4 + (pw + 2*ss);
        ws[t] = w[gtap*96 + rem];
    }
    // stage 6 rows x 66 cols x 32 ch (zeros outside image)
    for (int slot = t; slot < 6*66*8; slot += 256) {
        int row = slot / 528;
        int rem = slot - row*528;
        int yy = rem >> 3, c4 = rem & 7;
        int xi = R0 - 1 + row;
        float4 v = make_float4(0.f,0.f,0.f,0.f);
        if (yy >= 1 && yy <= 64 && xi >= 0 && xi < 64)
            v = *(const float4*)(x + (((n*64 + xi)*64) + (yy-1))*32 + c4*4);
        float* dst = xs + (row*66 + yy)*33 + c4*4;
        dst[0]=v.x; dst[1]=v.y; dst[2]=v.z; dst[3]=v.w;
    }
    __syncthreads();

    const int r4 = t >> 6, whc = t & 63;
    float a0 = bias[0], a1 = bias[1], a2 = bias[2];
#pragma unroll
    for (int rr = 0; rr < 2; ++rr) {
#pragma unroll
        for (int ss = 0; ss < 2; ++ss) {
            const float* wt = ws + (rr*2+ss)*96;
            const float* xp = xs + ((r4 + ph + rr)*66 + (whc + pw + ss))*33;
#pragma unroll
            for (int c4 = 0; c4 < 8; ++c4) {
                // 12 contiguous weights = 3 float4 (16B aligned: 48B steps)
                float4 wA = *(const float4*)(wt + c4*12 + 0);
                float4 wB = *(const float4*)(wt + c4*12 + 4);
                float4 wC = *(const float4*)(wt + c4*12 + 8);
                float x0 = xp[4*c4+0], x1 = xp[4*c4+1], x2 = xp[4*c4+2], x3 = xp[4*c4+3];
                a0 = fmaf(x0, wA.x, a0); a1 = fmaf(x0, wA.y, a1); a2 = fmaf(x0, wA.z, a2);
                a0 = fmaf(x1, wA.w, a0); a1 = fmaf(x1, wB.x, a1); a2 = fmaf(x1, wB.y, a2);
                a0 = fmaf(x2, wB.z, a0); a1 = fmaf(x2, wB.w, a1); a2 = fmaf(x2, wC.x, a2);
                a0 = fmaf(x3, wC.y, a0); a1 = fmaf(x3, wC.z, a1); a2 = fmaf(x3, wC.w, a2);
            }
        }
    }
    a0 = 1.0f / (1.0f + __expf(-a0));
    a1 = 1.0f / (1.0f + __expf(-a1));
    a2 = 1.0f / (1.0f + __expf(-a2));
    const int ho = 2*(R0 + r4) + ph, wo = 2*whc + pw;
    float* yp = y + ((n*128 + ho)*128 + wo)*3;
    yp[0] = a0; yp[1] = a1; yp[2] = a2;
}

__global__ void zero_loss(float* p) {
    if (threadIdx.x == 0 && blockIdx.x == 0) *p = 0.0f;
}

// ---- VQ (unchanged, exact fp32) ----
__global__ __launch_bounds__(256) void vq_kernel(
    const float* __restrict__ z, const float* __restrict__ emb,
    float* __restrict__ q, float* __restrict__ idx_out,
    float* __restrict__ loss_out, float loss_scale)
{
    __shared__ float zs[64*65];
    __shared__ float es[64*64];
    __shared__ float gd[4*64];
    __shared__ int   gi[4*64];
    __shared__ float md[64];
    __shared__ int   mi[64];

    const int t = threadIdx.x;
    const int pos0 = blockIdx.x * 64;

    for (int j = t; j < 64*64; j += 256)
        zs[(j >> 6)*65 + (j & 63)] = z[pos0*64 + j];
    __syncthreads();

    const int pos = t & 63;
    const int grp = t >> 6;
    float zr[64];
#pragma unroll
    for (int d = 0; d < 64; ++d) zr[d] = zs[pos*65 + d];

    float bestd = 3.4e38f;
    int   besti = 0;

    for (int ck = 0; ck < 8; ++ck) {
        __syncthreads();
        for (int j = t; j < 4096; j += 256) es[j] = emb[ck*4096 + j];
        __syncthreads();
#pragma unroll
        for (int k = 0; k < 16; ++k) {
            const int cc = grp + 4*k;
            const float4* ep = (const float4*)(es + cc*64);
            float acc = 0.0f;
#pragma unroll
            for (int u = 0; u < 16; ++u) {
                float4 e = ep[u];
                float d0 = zr[4*u+0] - e.x;
                float d1 = zr[4*u+1] - e.y;
                float d2 = zr[4*u+2] - e.z;
                float d3 = zr[4*u+3] - e.w;
                acc = fmaf(d0,d0,acc); acc = fmaf(d1,d1,acc);
                acc = fmaf(d2,d2,acc); acc = fmaf(d3,d3,acc);
            }
            const int code = ck*64 + cc;
            if (acc < bestd) { bestd = acc; besti = code; }
        }
    }
    gd[grp*64 + pos] = bestd;
    gi[grp*64 + pos] = besti;
    __syncthreads();
    if (grp == 0) {
        float bd = gd[pos]; int bi = gi[pos];
#pragma unroll
        for (int g2 = 1; g2 < 4; ++g2) {
            float dv = gd[g2*64 + pos]; int iv = gi[g2*64 + pos];
            if (dv < bd || (dv == bd && iv < bi)) { bd = dv; bi = iv; }
        }
        md[pos] = bd; mi[pos] = bi;
        idx_out[pos0 + pos] = (float)bi;
    }
    __syncthreads();
    for (int j = t; j < 4096; j += 256) {
        int p = j >> 6, d = j & 63;
        q[pos0*64 + j] = emb[mi[p]*64 + d];
    }
    if (t == 0) {
        float s = 0.0f;
        for (int p = 0; p < 64; ++p) s += md[p];
        atomicAdd(loss_out, s * loss_scale);
    }
}

extern "C" void kernel_launch(void* const* d_in, const int* in_sizes, int n_in,
                              void* d_out, int out_size, void* d_ws, size_t ws_size,
                              hipStream_t stream)
{
    const float* x   = (const float*)d_in[0];
    const float* ew1 = (const float*)d_in[1];  const float* eb1 = (const float*)d_in[2];
    const float* ew2 = (const float*)d_in[3];  const float* eb2 = (const float*)d_in[4];
    const float* ew3 = (const float*)d_in[5];  const float* eb3 = (const float*)d_in[6];
    const float* ew4 = (const float*)d_in[7];  const float* eb4 = (const float*)d_in[8];
    const float* emb = (const float*)d_in[9];
    const float* dw1 = (const float*)d_in[10]; const float* db1 = (const float*)d_in[11];
    const float* dw2 = (const float*)d_in[12]; const float* db2 = (const float*)d_in[13];
    const float* dw3 = (const float*)d_in[14]; const float* db3 = (const float*)d_in[15];
    const float* dw4 = (const float*)d_in[16]; const float* db4 = (const float*)d_in[17];

    float* outy = (float*)d_out;          // y: 6291456
    float* outl = outy + 6291456;         // loss: 1
    float* outi = outl + 1;               // idx: 32768

    float* ws = (float*)d_ws;
    float* A  = ws;                // 16777216 floats
    float* Bb = A  + 16777216;     //  8388608
    float* C  = Bb + 8388608;      //  4194304
    float* D  = C  + 4194304;      //  2097152 (z)
    float* E  = D  + 2097152;      //  2097152 (q)

    // ---- encoder ----
    hipLaunchKernelGGL((conv_fp32<4,4,3,32,2,1,256,4,1>),   dim3(16384), dim3(256), 0, stream,
                       x, ew1, eb1, A, 128, 128, 128, 64, 64);
    hipLaunchKernelGGL((conv_v2<4,4,32,64,2,1,256,8,1>),    dim3(4096),  dim3(256), 0, stream,
                       A, ew2, eb2, Bb, 128, 64, 64, 32, 32);
    hipLaunchKernelGGL((conv_v2<4,4,64,128,2,1,256,8,1>),   dim3(2048),  dim3(256), 0, stream,
                       Bb, ew3, eb3, C, 128, 32, 32, 16, 16);
    hipLaunchKernelGGL((conv_v2<2,2,128,64,1,0,256,8,0>),   dim3(1024),  dim3(256), 0, stream,
                       C, ew4, eb4, D, 128, 16, 16, 16, 16);

    // ---- vector quantizer ----
    hipLaunchKernelGGL(zero_loss, dim3(1), dim3(64), 0, stream, outl);
    hipLaunchKernelGGL(vq_kernel, dim3(512), dim3(256), 0, stream,
                       D, emb, E, outi, outl, 0.25f / 2097152.0f);

    // ---- decoder ----
    hipLaunchKernelGGL((conv_v2<2,2,64,128,1,1,256,8,1>),   dim3(2048), dim3(256), 0, stream,
                       E, dw1, db1, C, 128, 16, 16, 16, 16);
    hipLaunchKernelGGL((convt_v2<128,64,256,8,1>), dim3(1024,4), dim3(256), 0, stream,
                       C, dw2, db2, Bb, 128, 16, 16);
    hipLaunchKernelGGL((convt_v2<64,32,256,8,1>),  dim3(2048,4), dim3(256), 0, stream,
                       Bb, dw3, db3, A, 128, 32, 32);
    hipLaunchKernelGGL(dec4_kernel, dim3(2048,4), dim3(256), 0, stream,
                       A, dw4, db4, outy);
}

// Round 3
// 2674.806 us; speedup vs baseline: 1.7750x; 1.7750x over previous
//
#include <hip/hip_runtime.h>
#include <hip/hip_bf16.h>

typedef __bf16 bf16x8_t __attribute__((ext_vector_type(8)));
typedef float  f32x4_t  __attribute__((ext_vector_type(4)));

__device__ inline bf16x8_t ld_bf16x8(const __hip_bfloat16* p) {
    return *reinterpret_cast<const bf16x8_t*>(p);
}
__device__ inline bf16x8_t zero_bf16x8() {
    bf16x8_t z;
#pragma unroll
    for (int i = 0; i < 8; ++i) z[i] = (__bf16)0.0f;
    return z;
}

// ---------------------------------------------------------------------------
// enc1: conv 4x4 s2 pad1, CIN=3, COUT=32. LDS-tiled, bitwise-identical
// accumulation order (r,s,c ascending) to the previous exact kernel.
// Block: out tile 16(h) x 32(w), thread = (hl, wl) pixel + pixel wl+16.
// ---------------------------------------------------------------------------
__global__ __launch_bounds__(256) void enc1_kernel(
    const float* __restrict__ x, const float* __restrict__ w,
    const float* __restrict__ bias, float* __restrict__ y)
{
    __shared__ float xs[34*66*3];   // 6732 floats
    __shared__ float wsm[1536];     // 4*4*3*32

    const int n  = blockIdx.x >> 3;
    const int th = (blockIdx.x >> 1) & 3;
    const int tw = blockIdx.x & 1;
    const int HO0 = th*16, WO0 = tw*32;
    const int HI0 = 2*HO0 - 1, WI0 = 2*WO0 - 1;
    const int t = threadIdx.x;

    for (int i = t; i < 1536; i += 256) wsm[i] = w[i];
    for (int i = t; i < 34*66*3; i += 256) {
        int row = i / 198; int j = i - row*198;
        int wi_l = j / 3;  int c = j - wi_l*3;
        int hi = HI0 + row, wi = WI0 + wi_l;
        float v = 0.0f;
        if (hi >= 0 && hi < 128 && wi >= 0 && wi < 128)
            v = x[((n*128 + hi)*128 + wi)*3 + c];
        xs[i] = v;
    }
    __syncthreads();

    const int wl = t & 15, hl = t >> 4;    // hl 0..15
    float acc0[32], acc1[32];
#pragma unroll
    for (int f4 = 0; f4 < 8; ++f4) {
        float4 bv = *(const float4*)(bias + 4*f4);
        acc0[4*f4+0]=bv.x; acc0[4*f4+1]=bv.y; acc0[4*f4+2]=bv.z; acc0[4*f4+3]=bv.w;
        acc1[4*f4+0]=bv.x; acc1[4*f4+1]=bv.y; acc1[4*f4+2]=bv.z; acc1[4*f4+3]=bv.w;
    }
    for (int r = 0; r < 4; ++r) {
#pragma unroll
        for (int s = 0; s < 4; ++s) {
#pragma unroll
            for (int c = 0; c < 3; ++c) {
                float xv0 = xs[(2*hl + r)*198 + (2*wl + s)*3 + c];
                float xv1 = xs[(2*hl + r)*198 + (2*(wl+16) + s)*3 + c];
                const float* wp = wsm + ((r*4 + s)*3 + c)*32;
#pragma unroll
                for (int f4 = 0; f4 < 8; ++f4) {
                    float4 wv = *(const float4*)(wp + 4*f4);
                    acc0[4*f4+0] = fmaf(xv0, wv.x, acc0[4*f4+0]);
                    acc0[4*f4+1] = fmaf(xv0, wv.y, acc0[4*f4+1]);
                    acc0[4*f4+2] = fmaf(xv0, wv.z, acc0[4*f4+2]);
                    acc0[4*f4+3] = fmaf(xv0, wv.w, acc0[4*f4+3]);
                    acc1[4*f4+0] = fmaf(xv1, wv.x, acc1[4*f4+0]);
                    acc1[4*f4+1] = fmaf(xv1, wv.y, acc1[4*f4+1]);
                    acc1[4*f4+2] = fmaf(xv1, wv.z, acc1[4*f4+2]);
                    acc1[4*f4+3] = fmaf(xv1, wv.w, acc1[4*f4+3]);
                }
            }
        }
    }
    float* y0 = y + ((size_t)((n*64 + HO0 + hl)*64) + WO0 + wl)*32;
#pragma unroll
    for (int f4 = 0; f4 < 8; ++f4) {
        float4 o0 = make_float4(fmaxf(acc0[4*f4+0],0.f), fmaxf(acc0[4*f4+1],0.f),
                                fmaxf(acc0[4*f4+2],0.f), fmaxf(acc0[4*f4+3],0.f));
        *(float4*)(y0 + 4*f4) = o0;
    }
    float* y1 = y0 + 16*32;
#pragma unroll
    for (int f4 = 0; f4 < 8; ++f4) {
        float4 o1 = make_float4(fmaxf(acc1[4*f4+0],0.f), fmaxf(acc1[4*f4+1],0.f),
                                fmaxf(acc1[4*f4+2],0.f), fmaxf(acc1[4*f4+3],0.f));
        *(float4*)(y1 + 4*f4) = o1;
    }
}

// ---- v2 conv (kept for enc2/enc3/enc4): float4 x loads over CIN, PPT=8 ----
template<int R,int S,int CIN,int COUT,int STR,int PAD,int BLK,int PPT,int ACT>
__global__ __launch_bounds__(BLK) void conv_v2(
    const float* __restrict__ x, const float* __restrict__ w,
    const float* __restrict__ bias, float* __restrict__ y,
    int N, int Hin, int Win, int Hout, int Wout)
{
    constexpr int GPB = BLK / COUT;
    const int t = threadIdx.x;
    const int f = t % COUT;
    const int g = t / COUT;
    const int base = (blockIdx.x * GPB + g) * PPT;
    const int HW = Hout * Wout;

    int nn[PPT], ho[PPT], wo[PPT];
    float acc[PPT];
    const float bv = bias[f];
#pragma unroll
    for (int j = 0; j < PPT; ++j) {
        int p = base + j;
        nn[j] = p / HW;
        int rem = p - nn[j]*HW;
        ho[j] = rem / Wout;
        wo[j] = rem - ho[j]*Wout;
        acc[j] = bv;
    }
#pragma unroll
    for (int r = 0; r < R; ++r) {
#pragma unroll
        for (int s = 0; s < S; ++s) {
            const float* wp = w + ((r*S + s)*CIN)*COUT + f;
            int xoff[PPT]; bool v[PPT];
#pragma unroll
            for (int j = 0; j < PPT; ++j) {
                int hi = ho[j]*STR - PAD + r;
                int wi = wo[j]*STR - PAD + s;
                v[j] = (hi >= 0) && (hi < Hin) && (wi >= 0) && (wi < Win);
                xoff[j] = v[j] ? ((nn[j]*Hin + hi)*Win + wi)*CIN : 0;
            }
#pragma unroll 2
            for (int c4 = 0; c4 < CIN/4; ++c4) {
                float4 xv[PPT];
#pragma unroll
                for (int j = 0; j < PPT; ++j) {
                    if (v[j]) xv[j] = *(const float4*)(x + xoff[j] + 4*c4);
                    else      xv[j] = make_float4(0.f,0.f,0.f,0.f);
                }
#pragma unroll
                for (int cc = 0; cc < 4; ++cc) {
                    float wv = wp[(4*c4 + cc)*COUT];
#pragma unroll
                    for (int j = 0; j < PPT; ++j) {
                        float xc = (cc==0)?xv[j].x:(cc==1)?xv[j].y:(cc==2)?xv[j].z:xv[j].w;
                        acc[j] = fmaf(xc, wv, acc[j]);
                    }
                }
            }
        }
    }
#pragma unroll
    for (int j = 0; j < PPT; ++j) {
        float o = acc[j];
        if (ACT == 1) o = fmaxf(o, 0.0f);
        y[(base + j)*COUT + f] = o;
    }
}

// ---------------------------------------------------------------------------
// Weight prep: w [TAPS, CIN, COUT] fp32 (HWIO flattened) -> wt [TAPS][COUT][CIN] bf16
// ---------------------------------------------------------------------------
__global__ void prep_wt(const float* __restrict__ w, __hip_bfloat16* __restrict__ wt,
                        int TAPS, int CIN, int COUT)
{
    int i = blockIdx.x*256 + threadIdx.x;
    int total = TAPS*CIN*COUT;
    if (i >= total) return;
    int c = i % CIN; int rem = i / CIN;
    int f = rem % COUT; int tap = rem / COUT;
    wt[i] = __float2bfloat16(w[(tap*CIN + c)*COUT + f]);
}

// ---------------------------------------------------------------------------
// MFMA decoder layer: 2x2-tap conv (CONVT=0: k2 s1 pad1-low; CONVT=1: convT
// 4x4 s2 per output-parity). Input bf16 NHWC [N, SW, SW, CIN], weights
// wt[tap][COUT][CIN] bf16, output bf16 NHWC, ReLU.
// Block: 4 waves, M-tile 64 pixels, each wave 16 rows x COUT cols.
// A-frag: lane holds A[m=lane&15][k=quad*8+j]; B-frag: B^T row n=lane&15.
// D: col=lane&15 (f), row=quad*4+reg (m).
// ---------------------------------------------------------------------------
template<int CIN,int COUT,int SWL,int CONVT>
__global__ __launch_bounds__(256) void mfma_dec(
    const __hip_bfloat16* __restrict__ xin,
    const __hip_bfloat16* __restrict__ wt,
    const float* __restrict__ bias,
    __hip_bfloat16* __restrict__ yout)
{
    constexpr int SW = 1 << SWL;
    constexpr int NF = COUT / 16;
    const int ph = CONVT ? (int)(blockIdx.y >> 1) : 0;
    const int pw = CONVT ? (int)(blockIdx.y & 1) : 0;
    const int t = threadIdx.x;
    const int wave = t >> 6, lane = t & 63;
    const int l15 = lane & 15, quad = lane >> 4;

    const int m  = blockIdx.x*64 + wave*16 + l15;
    const int wp_ = m & (SW-1);
    const int hp_ = (m >> SWL) & (SW-1);
    const int np_ = m >> (2*SWL);

    f32x4_t acc[NF];
#pragma unroll
    for (int nf = 0; nf < NF; ++nf) {
        float bv = bias[nf*16 + l15];
        acc[nf][0] = bv; acc[nf][1] = bv; acc[nf][2] = bv; acc[nf][3] = bv;
    }
    const bf16x8_t zv = zero_bf16x8();

#pragma unroll
    for (int rr = 0; rr < 2; ++rr) {
#pragma unroll
        for (int ss = 0; ss < 2; ++ss) {
            const int hi = hp_ + ph - 1 + rr;
            const int wi = wp_ + pw - 1 + ss;
            const bool v = (hi >= 0) && (hi < SW) && (wi >= 0) && (wi < SW);
            const int hic = v ? hi : 0, wic = v ? wi : 0;
            const int widx = CONVT ? ((ph + 2*rr)*4 + (pw + 2*ss)) : (rr*2 + ss);
            const __hip_bfloat16* ap = xin + (size_t)((np_*SW + hic)*SW + wic)*CIN + quad*8;
            const __hip_bfloat16* bp = wt + (size_t)(widx*COUT)*CIN + l15*CIN + quad*8;
#pragma unroll
            for (int k0 = 0; k0 < CIN; k0 += 32) {
                bf16x8_t a = v ? ld_bf16x8(ap + k0) : zv;
#pragma unroll
                for (int nf = 0; nf < NF; ++nf) {
                    bf16x8_t b = ld_bf16x8(bp + (size_t)nf*16*CIN + k0);
                    acc[nf] = __builtin_amdgcn_mfma_f32_16x16x32_bf16(a, b, acc[nf], 0, 0, 0);
                }
            }
        }
    }

    constexpr int HOUT = CONVT ? 2*SW : SW;
#pragma unroll
    for (int nf = 0; nf < NF; ++nf) {
#pragma unroll
        for (int i = 0; i < 4; ++i) {
            int mo = blockIdx.x*64 + wave*16 + quad*4 + i;
            int wo = mo & (SW-1), ho = (mo >> SWL) & (SW-1), no = mo >> (2*SWL);
            int hoo = CONVT ? 2*ho + ph : ho;
            int woo = CONVT ? 2*wo + pw : wo;
            float vv = fmaxf(acc[nf][i], 0.0f);
            yout[((size_t)(no*HOUT + hoo)*HOUT + woo)*COUT + nf*16 + l15] = __float2bfloat16(vv);
        }
    }
}

// ---------------------------------------------------------------------------
// dec4: convT 4x4 s2, CIN=32 (bf16 in), COUT=3, sigmoid, fp32 math.
// ---------------------------------------------------------------------------
__global__ __launch_bounds__(256) void dec4_kernel(
    const __hip_bfloat16* __restrict__ x, const float* __restrict__ w,
    const float* __restrict__ bias, float* __restrict__ y)
{
    __shared__ float xs[6*66*33];
    __shared__ float ws[4*32*3];

    const int ph = blockIdx.y >> 1, pw = blockIdx.y & 1;
    const int n  = blockIdx.x >> 4;
    const int R0 = (blockIdx.x & 15) * 4;
    const int t  = threadIdx.x;

    if (t < 384) {
        int tap = t / 96, rem = t - tap*96;
        int rr = tap >> 1, ss = tap & 1;
        int gtap = (ph + 2*rr)*4 + (pw + 2*ss);
        ws[t] = w[gtap*96 + rem];
    }
    for (int slot = t; slot < 6*66*4; slot += 256) {
        int row = slot / 264;
        int rem = slot - row*264;
        int yy = rem >> 2, c8 = rem & 3;
        int xi = R0 - 1 + row;
        float4 raw = make_float4(0.f,0.f,0.f,0.f);
        if (yy >= 1 && yy <= 64 && xi >= 0 && xi < 64)
            raw = *(const float4*)((const char*)x + (size_t)((((n*64 + xi)*64) + (yy-1))*32 + c8*8)*2);
        union { float4 f; unsigned short u[8]; } uu; uu.f = raw;
        float* dst = xs + (row*66 + yy)*33 + c8*8;
#pragma unroll
        for (int jj = 0; jj < 8; ++jj) {
            unsigned int bb = ((unsigned int)uu.u[jj]) << 16;
            float fv; __builtin_memcpy(&fv, &bb, 4);
            dst[jj] = fv;
        }
    }
    __syncthreads();

    const int r4 = t >> 6, whc = t & 63;
    float a0 = bias[0], a1 = bias[1], a2 = bias[2];
#pragma unroll
    for (int rr = 0; rr < 2; ++rr) {
#pragma unroll
        for (int ss = 0; ss < 2; ++ss) {
            const float* wtp = ws + (rr*2+ss)*96;
            const float* xp = xs + ((r4 + ph + rr)*66 + (whc + pw + ss))*33;
#pragma unroll
            for (int c4 = 0; c4 < 8; ++c4) {
                float4 wA = *(const float4*)(wtp + c4*12 + 0);
                float4 wB = *(const float4*)(wtp + c4*12 + 4);
                float4 wC = *(const float4*)(wtp + c4*12 + 8);
                float x0 = xp[4*c4+0], x1 = xp[4*c4+1], x2 = xp[4*c4+2], x3 = xp[4*c4+3];
                a0 = fmaf(x0, wA.x, a0); a1 = fmaf(x0, wA.y, a1); a2 = fmaf(x0, wA.z, a2);
                a0 = fmaf(x1, wA.w, a0); a1 = fmaf(x1, wB.x, a1); a2 = fmaf(x1, wB.y, a2);
                a0 = fmaf(x2, wB.z, a0); a1 = fmaf(x2, wB.w, a1); a2 = fmaf(x2, wC.x, a2);
                a0 = fmaf(x3, wC.y, a0); a1 = fmaf(x3, wC.z, a1); a2 = fmaf(x3, wC.w, a2);
            }
        }
    }
    a0 = 1.0f / (1.0f + __expf(-a0));
    a1 = 1.0f / (1.0f + __expf(-a1));
    a2 = 1.0f / (1.0f + __expf(-a2));
    const int ho = 2*(R0 + r4) + ph, wo = 2*whc + pw;
    float* yp = y + ((size_t)(n*128 + ho)*128 + wo)*3;
    yp[0] = a0; yp[1] = a1; yp[2] = a2;
}

__global__ void zero_loss(float* p) {
    if (threadIdx.x == 0 && blockIdx.x == 0) *p = 0.0f;
}

// ---- VQ (exact fp32 distances; q emitted as bf16) ----
__global__ __launch_bounds__(256) void vq_kernel(
    const float* __restrict__ z, const float* __restrict__ emb,
    __hip_bfloat16* __restrict__ qb, float* __restrict__ idx_out,
    float* __restrict__ loss_out, float loss_scale)
{
    __shared__ float zs[64*65];
    __shared__ float es[64*64];
    __shared__ float gd[4*64];
    __shared__ int   gi[4*64];
    __shared__ float md[64];
    __shared__ int   mi[64];

    const int t = threadIdx.x;
    const int pos0 = blockIdx.x * 64;

    for (int j = t; j < 64*64; j += 256)
        zs[(j >> 6)*65 + (j & 63)] = z[pos0*64 + j];
    __syncthreads();

    const int pos = t & 63;
    const int grp = t >> 6;
    float zr[64];
#pragma unroll
    for (int d = 0; d < 64; ++d) zr[d] = zs[pos*65 + d];

    float bestd = 3.4e38f;
    int   besti = 0;

    for (int ck = 0; ck < 8; ++ck) {
        __syncthreads();
        for (int j = t; j < 4096; j += 256) es[j] = emb[ck*4096 + j];
        __syncthreads();
#pragma unroll
        for (int k = 0; k < 16; ++k) {
            const int cc = grp + 4*k;
            const float4* ep = (const float4*)(es + cc*64);
            float acc = 0.0f;
#pragma unroll
            for (int u = 0; u < 16; ++u) {
                float4 e = ep[u];
                float d0 = zr[4*u+0] - e.x;
                float d1 = zr[4*u+1] - e.y;
                float d2 = zr[4*u+2] - e.z;
                float d3 = zr[4*u+3] - e.w;
                acc = fmaf(d0,d0,acc); acc = fmaf(d1,d1,acc);
                acc = fmaf(d2,d2,acc); acc = fmaf(d3,d3,acc);
            }
            const int code = ck*64 + cc;
            if (acc < bestd) { bestd = acc; besti = code; }
        }
    }
    gd[grp*64 + pos] = bestd;
    gi[grp*64 + pos] = besti;
    __syncthreads();
    if (grp == 0) {
        float bd = gd[pos]; int bi = gi[pos];
#pragma unroll
        for (int g2 = 1; g2 < 4; ++g2) {
            float dv = gd[g2*64 + pos]; int iv = gi[g2*64 + pos];
            if (dv < bd || (dv == bd && iv < bi)) { bd = dv; bi = iv; }
        }
        md[pos] = bd; mi[pos] = bi;
        idx_out[pos0 + pos] = (float)bi;
    }
    __syncthreads();
    for (int j = t; j < 4096; j += 256) {
        int p = j >> 6, d = j & 63;
        qb[pos0*64 + j] = __float2bfloat16(emb[mi[p]*64 + d]);
    }
    if (t == 0) {
        float s = 0.0f;
        for (int p = 0; p < 64; ++p) s += md[p];
        atomicAdd(loss_out, s * loss_scale);
    }
}

extern "C" void kernel_launch(void* const* d_in, const int* in_sizes, int n_in,
                              void* d_out, int out_size, void* d_ws, size_t ws_size,
                              hipStream_t stream)
{
    const float* x   = (const float*)d_in[0];
    const float* ew1 = (const float*)d_in[1];  const float* eb1 = (const float*)d_in[2];
    const float* ew2 = (const float*)d_in[3];  const float* eb2 = (const float*)d_in[4];
    const float* ew3 = (const float*)d_in[5];  const float* eb3 = (const float*)d_in[6];
    const float* ew4 = (const float*)d_in[7];  const float* eb4 = (const float*)d_in[8];
    const float* emb = (const float*)d_in[9];
    const float* dw1 = (const float*)d_in[10]; const float* db1 = (const float*)d_in[11];
    const float* dw2 = (const float*)d_in[12]; const float* db2 = (const float*)d_in[13];
    const float* dw3 = (const float*)d_in[14]; const float* db3 = (const float*)d_in[15];
    const float* dw4 = (const float*)d_in[16]; const float* db4 = (const float*)d_in[17];

    float* outy = (float*)d_out;          // y: 6291456
    float* outl = outy + 6291456;         // loss: 1
    float* outi = outl + 1;               // idx: 32768

    float* ws = (float*)d_ws;
    float* A  = ws;                // enc1 out (64MB); reused for decoder bf16 bufs
    float* Bb = A  + 16777216;     // enc2 out
    float* C  = Bb + 8388608;      // enc3 out
    float* D  = C  + 4194304;      // z
    // bf16 region (old q slot, 8 MB):
    __hip_bfloat16* qb  = (__hip_bfloat16*)(D + 2097152);   // 2097152 elems
    __hip_bfloat16* wt1 = qb  + 2097152;                    // 4*128*64   = 32768
    __hip_bfloat16* wt2 = wt1 + 32768;                      // 16*64*128  = 131072
    __hip_bfloat16* wt3 = wt2 + 131072;                     // 16*32*64   = 32768
    // decoder intermediates overlay the (consumed) enc1-out region A:
    __hip_bfloat16* d1o = (__hip_bfloat16*)A;               // 4194304  elems
    __hip_bfloat16* d2o = d1o + 4194304;                    // 8388608  elems
    __hip_bfloat16* d3o = d2o + 8388608;                    // 16777216 elems

    // ---- weight prep (independent of encoder) ----
    hipLaunchKernelGGL(prep_wt, dim3((4*64*128 + 255)/256),  dim3(256), 0, stream, dw1, wt1, 4, 64, 128);
    hipLaunchKernelGGL(prep_wt, dim3((16*128*64 + 255)/256), dim3(256), 0, stream, dw2, wt2, 16, 128, 64);
    hipLaunchKernelGGL(prep_wt, dim3((16*64*32 + 255)/256),  dim3(256), 0, stream, dw3, wt3, 16, 64, 32);

    // ---- encoder (fp32, bitwise-stable) ----
    hipLaunchKernelGGL(enc1_kernel, dim3(1024), dim3(256), 0, stream, x, ew1, eb1, A);
    hipLaunchKernelGGL((conv_v2<4,4,32,64,2,1,256,8,1>),  dim3(4096), dim3(256), 0, stream,
                       A, ew2, eb2, Bb, 128, 64, 64, 32, 32);
    hipLaunchKernelGGL((conv_v2<4,4,64,128,2,1,256,8,1>), dim3(2048), dim3(256), 0, stream,
                       Bb, ew3, eb3, C, 128, 32, 32, 16, 16);
    hipLaunchKernelGGL((conv_v2<2,2,128,64,1,0,256,8,0>), dim3(1024), dim3(256), 0, stream,
                       C, ew4, eb4, D, 128, 16, 16, 16, 16);

    // ---- vector quantizer ----
    hipLaunchKernelGGL(zero_loss, dim3(1), dim3(64), 0, stream, outl);
    hipLaunchKernelGGL(vq_kernel, dim3(512), dim3(256), 0, stream,
                       D, emb, qb, outi, outl, 0.25f / 2097152.0f);

    // ---- decoder (bf16 MFMA) ----
    hipLaunchKernelGGL((mfma_dec<64,128,4,0>), dim3(512,1),  dim3(256), 0, stream, qb,  wt1, db1, d1o);
    hipLaunchKernelGGL((mfma_dec<128,64,4,1>), dim3(512,4),  dim3(256), 0, stream, d1o, wt2, db2, d2o);
    hipLaunchKernelGGL((mfma_dec<64,32,5,1>),  dim3(2048,4), dim3(256), 0, stream, d2o, wt3, db3, d3o);
    hipLaunchKernelGGL(dec4_kernel, dim3(2048,4), dim3(256), 0, stream, d3o, dw4, db4, outy);
}

// Round 6
// 920.213 us; speedup vs baseline: 5.1594x; 2.9067x over previous
//
#include <hip/hip_runtime.h>
#include <hip/hip_bf16.h>

typedef __bf16 bf16x8_t __attribute__((ext_vector_type(8)));
typedef float  f32x4_t  __attribute__((ext_vector_type(4)));

__device__ inline bf16x8_t ld_bf16x8(const __hip_bfloat16* p) {
    return *reinterpret_cast<const bf16x8_t*>(p);
}
__device__ inline bf16x8_t zero_bf16x8() {
    bf16x8_t z;
#pragma unroll
    for (int i = 0; i < 8; ++i) z[i] = (__bf16)0.0f;
    return z;
}

// Exact 3-way bf16 split: v == h + m + l exactly (truncation-based).
// h = v with low 16 bits masked; r = v-h exact (<=16 mantissa bits);
// m = mask(r); l = r-m exact (<=8 mantissa bits, bf16-exact).
__device__ inline void split3f(float v, __bf16& h, __bf16& m, __bf16& l) {
    unsigned u;  __builtin_memcpy(&u, &v, 4);
    unsigned uh = u & 0xffff0000u;
    float fh;    __builtin_memcpy(&fh, &uh, 4);
    float r = v - fh;
    unsigned ur; __builtin_memcpy(&ur, &r, 4);
    unsigned um = ur & 0xffff0000u;
    float fm;    __builtin_memcpy(&fm, &um, 4);
    float r2 = r - fm;
    unsigned ul; __builtin_memcpy(&ul, &r2, 4);
    unsigned short hs = (unsigned short)(uh >> 16);
    unsigned short ms = (unsigned short)(um >> 16);
    unsigned short ls = (unsigned short)(ul >> 16);
    __builtin_memcpy(&h, &hs, 2);
    __builtin_memcpy(&m, &ms, 2);
    __builtin_memcpy(&l, &ls, 2);
}

// ---------------------------------------------------------------------------
// enc1: conv 4x4 s2 pad1, CIN=3, COUT=32, exact fp32 (validated round 3).
// ---------------------------------------------------------------------------
__global__ __launch_bounds__(256) void enc1_kernel(
    const float* __restrict__ x, const float* __restrict__ w,
    const float* __restrict__ bias, float* __restrict__ y)
{
    __shared__ float xs[34*66*3];
    __shared__ float wsm[1536];

    const int n  = blockIdx.x >> 3;
    const int th = (blockIdx.x >> 1) & 3;
    const int tw = blockIdx.x & 1;
    const int HO0 = th*16, WO0 = tw*32;
    const int HI0 = 2*HO0 - 1, WI0 = 2*WO0 - 1;
    const int t = threadIdx.x;

    for (int i = t; i < 1536; i += 256) wsm[i] = w[i];
    for (int i = t; i < 34*66*3; i += 256) {
        int row = i / 198; int j = i - row*198;
        int wi_l = j / 3;  int c = j - wi_l*3;
        int hi = HI0 + row, wi = WI0 + wi_l;
        float v = 0.0f;
        if (hi >= 0 && hi < 128 && wi >= 0 && wi < 128)
            v = x[((n*128 + hi)*128 + wi)*3 + c];
        xs[i] = v;
    }
    __syncthreads();

    const int wl = t & 15, hl = t >> 4;
    float acc0[32], acc1[32];
#pragma unroll
    for (int f4 = 0; f4 < 8; ++f4) {
        float4 bv = *(const float4*)(bias + 4*f4);
        acc0[4*f4+0]=bv.x; acc0[4*f4+1]=bv.y; acc0[4*f4+2]=bv.z; acc0[4*f4+3]=bv.w;
        acc1[4*f4+0]=bv.x; acc1[4*f4+1]=bv.y; acc1[4*f4+2]=bv.z; acc1[4*f4+3]=bv.w;
    }
    for (int r = 0; r < 4; ++r) {
#pragma unroll
        for (int s = 0; s < 4; ++s) {
#pragma unroll
            for (int c = 0; c < 3; ++c) {
                float xv0 = xs[(2*hl + r)*198 + (2*wl + s)*3 + c];
                float xv1 = xs[(2*hl + r)*198 + (2*(wl+16) + s)*3 + c];
                const float* wp = wsm + ((r*4 + s)*3 + c)*32;
#pragma unroll
                for (int f4 = 0; f4 < 8; ++f4) {
                    float4 wv = *(const float4*)(wp + 4*f4);
                    acc0[4*f4+0] = fmaf(xv0, wv.x, acc0[4*f4+0]);
                    acc0[4*f4+1] = fmaf(xv0, wv.y, acc0[4*f4+1]);
                    acc0[4*f4+2] = fmaf(xv0, wv.z, acc0[4*f4+2]);
                    acc0[4*f4+3] = fmaf(xv0, wv.w, acc0[4*f4+3]);
                    acc1[4*f4+0] = fmaf(xv1, wv.x, acc1[4*f4+0]);
                    acc1[4*f4+1] = fmaf(xv1, wv.y, acc1[4*f4+1]);
                    acc1[4*f4+2] = fmaf(xv1, wv.z, acc1[4*f4+2]);
                    acc1[4*f4+3] = fmaf(xv1, wv.w, acc1[4*f4+3]);
                }
            }
        }
    }
    float* y0 = y + ((size_t)((n*64 + HO0 + hl)*64) + WO0 + wl)*32;
#pragma unroll
    for (int f4 = 0; f4 < 8; ++f4) {
        float4 o0 = make_float4(fmaxf(acc0[4*f4+0],0.f), fmaxf(acc0[4*f4+1],0.f),
                                fmaxf(acc0[4*f4+2],0.f), fmaxf(acc0[4*f4+3],0.f));
        *(float4*)(y0 + 4*f4) = o0;
    }
    float* y1 = y0 + 16*32;
#pragma unroll
    for (int f4 = 0; f4 < 8; ++f4) {
        float4 o1 = make_float4(fmaxf(acc1[4*f4+0],0.f), fmaxf(acc1[4*f4+1],0.f),
                                fmaxf(acc1[4*f4+2],0.f), fmaxf(acc1[4*f4+3],0.f));
        *(float4*)(y1 + 4*f4) = o1;
    }
}

// ---------------------------------------------------------------------------
// Weight prep: HWIO fp32 [tap][CIN][COUT] -> [tap][COUT][CIN]
//   prep_wt : single bf16 (decoder)
//   prep_wt3: exact 3-way split planes (encoder)
// ---------------------------------------------------------------------------
__global__ void prep_wt(const float* __restrict__ w, __hip_bfloat16* __restrict__ wt,
                        int TAPS, int CIN, int COUT)
{
    int i = blockIdx.x*256 + threadIdx.x;
    if (i >= TAPS*CIN*COUT) return;
    int c = i % CIN; int rem = i / CIN;
    int f = rem % COUT; int tap = rem / COUT;
    wt[i] = __float2bfloat16(w[(tap*CIN + c)*COUT + f]);
}

__global__ void prep_wt3(const float* __restrict__ w,
                         __hip_bfloat16* __restrict__ wh, __hip_bfloat16* __restrict__ wm,
                         __hip_bfloat16* __restrict__ wl,
                         int TAPS, int CIN, int COUT)
{
    int i = blockIdx.x*256 + threadIdx.x;
    if (i >= TAPS*CIN*COUT) return;
    int c = i % CIN; int rem = i / CIN;
    int f = rem % COUT; int tap = rem / COUT;
    float v = w[(tap*CIN + c)*COUT + f];
    __bf16 h, m, l;
    split3f(v, h, m, l);
    ((__bf16*)wh)[i] = h; ((__bf16*)wm)[i] = m; ((__bf16*)wl)[i] = l;
}

// ---------------------------------------------------------------------------
// bf16x3 MFMA encoder conv (fp32-accurate): RxS taps, stride STR, pad PAD.
// x = xh+xm+xl exactly (or split on the fly from fp32 when INF32).
// acc accumulates 6 product terms (hh,hm,mh,hl,lh,mm); dropped terms are
// <= ~2^-26 relative -> below fp32 ulp. Weights pre-split exactly.
// OUTF32=1: fp32 out (z). Else: exact 3-plane bf16 out (+ReLU if ACT).
// ---------------------------------------------------------------------------
template<int R,int S,int CIN,int COUT,int IWL,int OWL,int STR,int PAD,int ACT,int INF32,int OUTF32>
__global__ __launch_bounds__(256) void mfma_enc3(
    const float* __restrict__ xf32,
    const __hip_bfloat16* __restrict__ xh, const __hip_bfloat16* __restrict__ xm,
    const __hip_bfloat16* __restrict__ xl,
    const __hip_bfloat16* __restrict__ wh, const __hip_bfloat16* __restrict__ wm,
    const __hip_bfloat16* __restrict__ wl,
    const float* __restrict__ bias,
    __hip_bfloat16* __restrict__ yh, __hip_bfloat16* __restrict__ ym,
    __hip_bfloat16* __restrict__ yl2,
    float* __restrict__ yf)
{
    constexpr int IW = 1 << IWL, OW = 1 << OWL;
    constexpr int NF = COUT / 16, KC = CIN / 32;
    const int t = threadIdx.x;
    const int wave = t >> 6, lane = t & 63;
    const int l15 = lane & 15, quad = lane >> 4;

    const int m  = blockIdx.x*64 + wave*16 + l15;
    const int wp_ = m & (OW-1);
    const int hp_ = (m >> OWL) & (OW-1);
    const int np_ = m >> (2*OWL);

    f32x4_t acc[NF];
#pragma unroll
    for (int nf = 0; nf < NF; ++nf) {
        float bv = bias[nf*16 + l15];
        acc[nf][0] = bv; acc[nf][1] = bv; acc[nf][2] = bv; acc[nf][3] = bv;
    }
    const bf16x8_t zv = zero_bf16x8();

#pragma unroll
    for (int r = 0; r < R; ++r) {
#pragma unroll
        for (int s = 0; s < S; ++s) {
            const int hi = hp_*STR - PAD + r;
            const int wi = wp_*STR - PAD + s;
            const bool v = (hi >= 0) && (hi < IW) && (wi >= 0) && (wi < IW);
            const int hic = v ? hi : 0, wic = v ? wi : 0;
            const size_t abase = ((size_t)(np_*IW + hic)*IW + wic)*CIN + quad*8;
            const size_t bbase = (size_t)(r*S + s)*COUT*CIN + l15*CIN + quad*8;
#pragma unroll
            for (int kc = 0; kc < KC; ++kc) {
                bf16x8_t ah, am_, al_;
                if (INF32) {
                    float xv[8];
                    if (v) {
                        *(float4*)(xv+0) = *(const float4*)(xf32 + abase + kc*32);
                        *(float4*)(xv+4) = *(const float4*)(xf32 + abase + kc*32 + 4);
                    } else {
#pragma unroll
                        for (int j = 0; j < 8; ++j) xv[j] = 0.0f;
                    }
#pragma unroll
                    for (int j = 0; j < 8; ++j) {
                        __bf16 th, tm, tl;
                        split3f(xv[j], th, tm, tl);
                        ah[j] = th; am_[j] = tm; al_[j] = tl;
                    }
                } else {
                    ah  = v ? ld_bf16x8(xh + abase + kc*32) : zv;
                    am_ = v ? ld_bf16x8(xm + abase + kc*32) : zv;
                    al_ = v ? ld_bf16x8(xl + abase + kc*32) : zv;
                }
#pragma unroll
                for (int nf = 0; nf < NF; ++nf) {
                    const size_t bo = bbase + (size_t)nf*16*CIN + kc*32;
                    bf16x8_t bh = ld_bf16x8(wh + bo);
                    bf16x8_t bm = ld_bf16x8(wm + bo);
                    bf16x8_t bl = ld_bf16x8(wl + bo);
                    // small terms first
                    acc[nf] = __builtin_amdgcn_mfma_f32_16x16x32_bf16(al_, bh, acc[nf], 0, 0, 0);
                    acc[nf] = __builtin_amdgcn_mfma_f32_16x16x32_bf16(ah,  bl, acc[nf], 0, 0, 0);
                    acc[nf] = __builtin_amdgcn_mfma_f32_16x16x32_bf16(am_, bm, acc[nf], 0, 0, 0);
                    acc[nf] = __builtin_amdgcn_mfma_f32_16x16x32_bf16(am_, bh, acc[nf], 0, 0, 0);
                    acc[nf] = __builtin_amdgcn_mfma_f32_16x16x32_bf16(ah,  bm, acc[nf], 0, 0, 0);
                    acc[nf] = __builtin_amdgcn_mfma_f32_16x16x32_bf16(ah,  bh, acc[nf], 0, 0, 0);
                }
            }
        }
    }

#pragma unroll
    for (int nf = 0; nf < NF; ++nf) {
#pragma unroll
        for (int i = 0; i < 4; ++i) {
            int mo = blockIdx.x*64 + wave*16 + quad*4 + i;
            int wo = mo & (OW-1), ho = (mo >> OWL) & (OW-1), no = mo >> (2*OWL);
            size_t oidx = ((size_t)(no*OW + ho)*OW + wo)*COUT + nf*16 + l15;
            float vv = acc[nf][i];
            if (ACT) vv = fmaxf(vv, 0.0f);
            if (OUTF32) {
                yf[oidx] = vv;
            } else {
                __bf16 h, mm2, l;
                split3f(vv, h, mm2, l);
                ((__bf16*)yh)[oidx]  = h;
                ((__bf16*)ym)[oidx]  = mm2;
                ((__bf16*)yl2)[oidx] = l;
            }
        }
    }
}

// ---------------------------------------------------------------------------
// MFMA decoder layer (validated round 3): plain bf16.
// ---------------------------------------------------------------------------
template<int CIN,int COUT,int SWL,int CONVT>
__global__ __launch_bounds__(256) void mfma_dec(
    const __hip_bfloat16* __restrict__ xin,
    const __hip_bfloat16* __restrict__ wt,
    const float* __restrict__ bias,
    __hip_bfloat16* __restrict__ yout)
{
    constexpr int SW = 1 << SWL;
    constexpr int NF = COUT / 16;
    const int ph = CONVT ? (int)(blockIdx.y >> 1) : 0;
    const int pw = CONVT ? (int)(blockIdx.y & 1) : 0;
    const int t = threadIdx.x;
    const int wave = t >> 6, lane = t & 63;
    const int l15 = lane & 15, quad = lane >> 4;

    const int m  = blockIdx.x*64 + wave*16 + l15;
    const int wp_ = m & (SW-1);
    const int hp_ = (m >> SWL) & (SW-1);
    const int np_ = m >> (2*SWL);

    f32x4_t acc[NF];
#pragma unroll
    for (int nf = 0; nf < NF; ++nf) {
        float bv = bias[nf*16 + l15];
        acc[nf][0] = bv; acc[nf][1] = bv; acc[nf][2] = bv; acc[nf][3] = bv;
    }
    const bf16x8_t zv = zero_bf16x8();

#pragma unroll
    for (int rr = 0; rr < 2; ++rr) {
#pragma unroll
        for (int ss = 0; ss < 2; ++ss) {
            const int hi = hp_ + ph - 1 + rr;
            const int wi = wp_ + pw - 1 + ss;
            const bool v = (hi >= 0) && (hi < SW) && (wi >= 0) && (wi < SW);
            const int hic = v ? hi : 0, wic = v ? wi : 0;
            const int widx = CONVT ? ((ph + 2*rr)*4 + (pw + 2*ss)) : (rr*2 + ss);
            const __hip_bfloat16* ap = xin + (size_t)((np_*SW + hic)*SW + wic)*CIN + quad*8;
            const __hip_bfloat16* bp = wt + (size_t)(widx*COUT)*CIN + l15*CIN + quad*8;
#pragma unroll
            for (int k0 = 0; k0 < CIN; k0 += 32) {
                bf16x8_t a = v ? ld_bf16x8(ap + k0) : zv;
#pragma unroll
                for (int nf = 0; nf < NF; ++nf) {
                    bf16x8_t b = ld_bf16x8(bp + (size_t)nf*16*CIN + k0);
                    acc[nf] = __builtin_amdgcn_mfma_f32_16x16x32_bf16(a, b, acc[nf], 0, 0, 0);
                }
            }
        }
    }

    constexpr int HOUT = CONVT ? 2*SW : SW;
#pragma unroll
    for (int nf = 0; nf < NF; ++nf) {
#pragma unroll
        for (int i = 0; i < 4; ++i) {
            int mo = blockIdx.x*64 + wave*16 + quad*4 + i;
            int wo = mo & (SW-1), ho = (mo >> SWL) & (SW-1), no = mo >> (2*SWL);
            int hoo = CONVT ? 2*ho + ph : ho;
            int woo = CONVT ? 2*wo + pw : wo;
            float vv = fmaxf(acc[nf][i], 0.0f);
            yout[((size_t)(no*HOUT + hoo)*HOUT + woo)*COUT + nf*16 + l15] = __float2bfloat16(vv);
        }
    }
}

// ---------------------------------------------------------------------------
// dec4: convT 4x4 s2, CIN=32 (bf16 in), COUT=3, sigmoid, fp32 math.
// ---------------------------------------------------------------------------
__global__ __launch_bounds__(256) void dec4_kernel(
    const __hip_bfloat16* __restrict__ x, const float* __restrict__ w,
    const float* __restrict__ bias, float* __restrict__ y)
{
    __shared__ float xs[6*66*33];
    __shared__ float ws[4*32*3];

    const int ph = blockIdx.y >> 1, pw = blockIdx.y & 1;
    const int n  = blockIdx.x >> 4;
    const int R0 = (blockIdx.x & 15) * 4;
    const int t  = threadIdx.x;

    if (t < 384) {
        int tap = t / 96, rem = t - tap*96;
        int rr = tap >> 1, ss = tap & 1;
        int gtap = (ph + 2*rr)*4 + (pw + 2*ss);
        ws[t] = w[gtap*96 + rem];
    }
    for (int slot = t; slot < 6*66*4; slot += 256) {
        int row = slot / 264;
        int rem = slot - row*264;
        int yy = rem >> 2, c8 = rem & 3;
        int xi = R0 - 1 + row;
        float4 raw = make_float4(0.f,0.f,0.f,0.f);
        if (yy >= 1 && yy <= 64 && xi >= 0 && xi < 64)
            raw = *(const float4*)((const char*)x + (size_t)((((n*64 + xi)*64) + (yy-1))*32 + c8*8)*2);
        union { float4 f; unsigned short u[8]; } uu; uu.f = raw;
        float* dst = xs + (row*66 + yy)*33 + c8*8;
#pragma unroll
        for (int jj = 0; jj < 8; ++jj) {
            unsigned int bb = ((unsigned int)uu.u[jj]) << 16;
            float fv; __builtin_memcpy(&fv, &bb, 4);
            dst[jj] = fv;
        }
    }
    __syncthreads();

    const int r4 = t >> 6, whc = t & 63;
    float a0 = bias[0], a1 = bias[1], a2 = bias[2];
#pragma unroll
    for (int rr = 0; rr < 2; ++rr) {
#pragma unroll
        for (int ss = 0; ss < 2; ++ss) {
            const float* wtp = ws + (rr*2+ss)*96;
            const float* xp = xs + ((r4 + ph + rr)*66 + (whc + pw + ss))*33;
#pragma unroll
            for (int c4 = 0; c4 < 8; ++c4) {
                float4 wA = *(const float4*)(wtp + c4*12 + 0);
                float4 wB = *(const float4*)(wtp + c4*12 + 4);
                float4 wC = *(const float4*)(wtp + c4*12 + 8);
                float x0 = xp[4*c4+0], x1 = xp[4*c4+1], x2 = xp[4*c4+2], x3 = xp[4*c4+3];
                a0 = fmaf(x0, wA.x, a0); a1 = fmaf(x0, wA.y, a1); a2 = fmaf(x0, wA.z, a2);
                a0 = fmaf(x1, wA.w, a0); a1 = fmaf(x1, wB.x, a1); a2 = fmaf(x1, wB.y, a2);
                a0 = fmaf(x2, wB.z, a0); a1 = fmaf(x2, wB.w, a1); a2 = fmaf(x2, wC.x, a2);
                a0 = fmaf(x3, wC.y, a0); a1 = fmaf(x3, wC.z, a1); a2 = fmaf(x3, wC.w, a2);
            }
        }
    }
    a0 = 1.0f / (1.0f + __expf(-a0));
    a1 = 1.0f / (1.0f + __expf(-a1));
    a2 = 1.0f / (1.0f + __expf(-a2));
    const int ho = 2*(R0 + r4) + ph, wo = 2*whc + pw;
    float* yp = y + ((size_t)(n*128 + ho)*128 + wo)*3;
    yp[0] = a0; yp[1] = a1; yp[2] = a2;
}

__global__ void zero_loss(float* p) {
    if (threadIdx.x == 0 && blockIdx.x == 0) *p = 0.0f;
}

// ---- VQ (exact fp32 distances; q emitted as bf16) ----
__global__ __launch_bounds__(256) void vq_kernel(
    const float* __restrict__ z, const float* __restrict__ emb,
    __hip_bfloat16* __restrict__ qb, float* __restrict__ idx_out,
    float* __restrict__ loss_out, float loss_scale)
{
    __shared__ float zs[64*65];
    __shared__ float es[64*64];
    __shared__ float gd[4*64];
    __shared__ int   gi[4*64];
    __shared__ float md[64];
    __shared__ int   mi[64];

    const int t = threadIdx.x;
    const int pos0 = blockIdx.x * 64;

    for (int j = t; j < 64*64; j += 256)
        zs[(j >> 6)*65 + (j & 63)] = z[pos0*64 + j];
    __syncthreads();

    const int pos = t & 63;
    const int grp = t >> 6;
    float zr[64];
#pragma unroll
    for (int d = 0; d < 64; ++d) zr[d] = zs[pos*65 + d];

    float bestd = 3.4e38f;
    int   besti = 0;

    for (int ck = 0; ck < 8; ++ck) {
        __syncthreads();
        for (int j = t; j < 4096; j += 256) es[j] = emb[ck*4096 + j];
        __syncthreads();
#pragma unroll
        for (int k = 0; k < 16; ++k) {
            const int cc = grp + 4*k;
            const float4* ep = (const float4*)(es + cc*64);
            float acc = 0.0f;
#pragma unroll
            for (int u = 0; u < 16; ++u) {
                float4 e = ep[u];
                float d0 = zr[4*u+0] - e.x;
                float d1 = zr[4*u+1] - e.y;
                float d2 = zr[4*u+2] - e.z;
                float d3 = zr[4*u+3] - e.w;
                acc = fmaf(d0,d0,acc); acc = fmaf(d1,d1,acc);
                acc = fmaf(d2,d2,acc); acc = fmaf(d3,d3,acc);
            }
            const int code = ck*64 + cc;
            if (acc < bestd) { bestd = acc; besti = code; }
        }
    }
    gd[grp*64 + pos] = bestd;
    gi[grp*64 + pos] = besti;
    __syncthreads();
    if (grp == 0) {
        float bd = gd[pos]; int bi = gi[pos];
#pragma unroll
        for (int g2 = 1; g2 < 4; ++g2) {
            float dv = gd[g2*64 + pos]; int iv = gi[g2*64 + pos];
            if (dv < bd || (dv == bd && iv < bi)) { bd = dv; bi = iv; }
        }
        md[pos] = bd; mi[pos] = bi;
        idx_out[pos0 + pos] = (float)bi;
    }
    __syncthreads();
    for (int j = t; j < 4096; j += 256) {
        int p = j >> 6, d = j & 63;
        qb[pos0*64 + j] = __float2bfloat16(emb[mi[p]*64 + d]);
    }
    if (t == 0) {
        float s = 0.0f;
        for (int p = 0; p < 64; ++p) s += md[p];
        atomicAdd(loss_out, s * loss_scale);
    }
}

extern "C" void kernel_launch(void* const* d_in, const int* in_sizes, int n_in,
                              void* d_out, int out_size, void* d_ws, size_t ws_size,
                              hipStream_t stream)
{
    const float* x   = (const float*)d_in[0];
    const float* ew1 = (const float*)d_in[1];  const float* eb1 = (const float*)d_in[2];
    const float* ew2 = (const float*)d_in[3];  const float* eb2 = (const float*)d_in[4];
    const float* ew3 = (const float*)d_in[5];  const float* eb3 = (const float*)d_in[6];
    const float* ew4 = (const float*)d_in[7];  const float* eb4 = (const float*)d_in[8];
    const float* emb = (const float*)d_in[9];
    const float* dw1 = (const float*)d_in[10]; const float* db1 = (const float*)d_in[11];
    const float* dw2 = (const float*)d_in[12]; const float* db2 = (const float*)d_in[13];
    const float* dw3 = (const float*)d_in[14]; const float* db3 = (const float*)d_in[15];
    const float* dw4 = (const float*)d_in[16]; const float* db4 = (const float*)d_in[17];

    float* outy = (float*)d_out;          // y: 6291456
    float* outl = outy + 6291456;         // loss: 1
    float* outi = outl + 1;               // idx: 32768

    // Workspace layout (time-multiplexed; peak ~119 MB < 134 MB proven):
    char* W = (char*)d_ws;
    float*          e1  = (float*)         (W + 0);          // 16,777,216 el f32 [0,67108864)
    __hip_bfloat16* e2h = (__hip_bfloat16*)(W + 67108864);   // 8,388,608 el
    __hip_bfloat16* e2m = (__hip_bfloat16*)(W + 83886080);
    __hip_bfloat16* e2l = (__hip_bfloat16*)(W + 100663296);  // ends 117440512
    __hip_bfloat16* e3h = (__hip_bfloat16*)(W + 0);          // 4,194,304 el (over dead e1)
    __hip_bfloat16* e3m = (__hip_bfloat16*)(W + 8388608);
    __hip_bfloat16* e3l = (__hip_bfloat16*)(W + 16777216);
    float*          z   = (float*)         (W + 25165824);   // 2,097,152 el f32
    __hip_bfloat16* qb  = (__hip_bfloat16*)(W + 33554432);   // 2,097,152 el
    __hip_bfloat16* d1o = (__hip_bfloat16*)(W + 67108864);   // 4,194,304 el (over dead e2)
    __hip_bfloat16* d2o = (__hip_bfloat16*)(W + 75497472);   // 8,388,608 el
    __hip_bfloat16* d3o = (__hip_bfloat16*)(W + 0);          // 16,777,216 el (over dead e3/z)
    // persistent weights (never overlaid):
    __hip_bfloat16* wh2 = (__hip_bfloat16*)(W + 117440512);  // 32768 el each
    __hip_bfloat16* wm2 = wh2 + 32768;
    __hip_bfloat16* wl2 = wm2 + 32768;
    __hip_bfloat16* wh3 = wl2 + 32768;                       // 131072 el each
    __hip_bfloat16* wm3 = wh3 + 131072;
    __hip_bfloat16* wl3 = wm3 + 131072;
    __hip_bfloat16* wh4 = wl3 + 131072;                      // 32768 el each
    __hip_bfloat16* wm4 = wh4 + 32768;
    __hip_bfloat16* wl4 = wm4 + 32768;
    __hip_bfloat16* wt1 = wl4 + 32768;                       // 32768
    __hip_bfloat16* wt2 = wt1 + 32768;                       // 131072
    __hip_bfloat16* wt3 = wt2 + 131072;                      // 32768

    // ---- weight prep ----
    hipLaunchKernelGGL(prep_wt3, dim3(128), dim3(256), 0, stream, ew2, wh2, wm2, wl2, 16, 32, 64);
    hipLaunchKernelGGL(prep_wt3, dim3(512), dim3(256), 0, stream, ew3, wh3, wm3, wl3, 16, 64, 128);
    hipLaunchKernelGGL(prep_wt3, dim3(128), dim3(256), 0, stream, ew4, wh4, wm4, wl4, 4, 128, 64);
    hipLaunchKernelGGL(prep_wt,  dim3(128), dim3(256), 0, stream, dw1, wt1, 4, 64, 128);
    hipLaunchKernelGGL(prep_wt,  dim3(512), dim3(256), 0, stream, dw2, wt2, 16, 128, 64);
    hipLaunchKernelGGL(prep_wt,  dim3(128), dim3(256), 0, stream, dw3, wt3, 16, 64, 32);

    // ---- encoder (fp32-accurate bf16x3 MFMA) ----
    hipLaunchKernelGGL(enc1_kernel, dim3(1024), dim3(256), 0, stream, x, ew1, eb1, e1);
    hipLaunchKernelGGL((mfma_enc3<4,4,32,64,6,5,2,1,1,1,0>), dim3(2048), dim3(256), 0, stream,
                       e1, (const __hip_bfloat16*)nullptr, (const __hip_bfloat16*)nullptr,
                       (const __hip_bfloat16*)nullptr,
                       wh2, wm2, wl2, eb2, e2h, e2m, e2l, (float*)nullptr);
    hipLaunchKernelGGL((mfma_enc3<4,4,64,128,5,4,2,1,1,0,0>), dim3(512), dim3(256), 0, stream,
                       (const float*)nullptr, e2h, e2m, e2l,
                       wh3, wm3, wl3, eb3, e3h, e3m, e3l, (float*)nullptr);
    hipLaunchKernelGGL((mfma_enc3<2,2,128,64,4,4,1,0,0,0,1>), dim3(512), dim3(256), 0, stream,
                       (const float*)nullptr, e3h, e3m, e3l,
                       wh4, wm4, wl4, eb4,
                       (__hip_bfloat16*)nullptr, (__hip_bfloat16*)nullptr,
                       (__hip_bfloat16*)nullptr, z);

    // ---- vector quantizer ----
    hipLaunchKernelGGL(zero_loss, dim3(1), dim3(64), 0, stream, outl);
    hipLaunchKernelGGL(vq_kernel, dim3(512), dim3(256), 0, stream,
                       z, emb, qb, outi, outl, 0.25f / 2097152.0f);

    // ---- decoder (bf16 MFMA, validated) ----
    hipLaunchKernelGGL((mfma_dec<64,128,4,0>), dim3(512,1),  dim3(256), 0, stream, qb,  wt1, db1, d1o);
    hipLaunchKernelGGL((mfma_dec<128,64,4,1>), dim3(512,4),  dim3(256), 0, stream, d1o, wt2, db2, d2o);
    hipLaunchKernelGGL((mfma_dec<64,32,5,1>),  dim3(2048,4), dim3(256), 0, stream, d2o, wt3, db3, d3o);
    hipLaunchKernelGGL(dec4_kernel, dim3(2048,4), dim3(256), 0, stream, d3o, dw4, db4, outy);
}